// Round 7
// baseline (323.956 us; speedup 1.0000x reference)
//
#include <hip/hip_runtime.h>
#include <math.h>

#define B_ 8
#define N_ 16384
#define G_ 128      // NUM_GROUPS
#define GS_ 32      // GROUP_SIZE
#define UK_ 128     // UPSCALE_K
#define FPS_T 512
#define FPS_W 8     // waves per FPS block
#define PPT 32      // points per thread (N_ / FPS_T), ALL coords in VGPRs
#define BQ_T 512
#define BQ_W 8      // waves per group block

// No mul+add contraction anywhere in this TU: per-op IEEE rounding must match
// the numpy reference exactly (((dx*dx + dy*dy) + dz*dz), each op rounded).
#pragma clang fp contract(off)

typedef float v2f __attribute__((ext_vector_type(2)));

// 64-bit max-combine with a DPP-shifted copy of vv (old=0 == identity for max).
#define DPP64_MAXSTEP(vv, ctrl, rmask)                                          \
  {                                                                             \
    unsigned _lo = (unsigned)__builtin_amdgcn_update_dpp(                       \
        0, (int)(unsigned)((vv) & 0xffffffffull), (ctrl), (rmask), 0xf, false); \
    unsigned _hi = (unsigned)__builtin_amdgcn_update_dpp(                       \
        0, (int)(unsigned)((vv) >> 32), (ctrl), (rmask), 0xf, false);           \
    unsigned long long _tv = ((unsigned long long)_hi << 32) | _lo;             \
    if (_tv > (vv)) (vv) = _tv;                                                 \
  }

// Exact-rounding distance^2, matching numpy: ((dx*dx + dy*dy) + dz*dz), no FMA.
__device__ __forceinline__ float dist2(float x, float y, float z,
                                       float cx, float cy, float cz) {
    float dx = __fsub_rn(x, cx);
    float dy = __fsub_rn(y, cy);
    float dz = __fsub_rn(z, cz);
    return __fadd_rn(__fadd_rn(__fmul_rn(dx, dx), __fmul_rn(dy, dy)),
                     __fmul_rn(dz, dz));
}

// ---------------------------------------------------------------------------
// Kernel 0: zero gl (ws is poisoned 0xAA; must be zeroed before group_kernel).
// ---------------------------------------------------------------------------
__global__ void init_kernel(int* __restrict__ gl) {
    int t = threadIdx.x;
    if (t < B_) gl[t] = 0;
}

// ---------------------------------------------------------------------------
// Kernel 1: FPS, ONE 512-thread block per batch + fused CNMS.
//
// r17 post-mortem of r16: step time ~4300cyc decomposes as LDS pipe ~1540
// (128KB re-read/step: 128 ds_read_b128 x 1024B at 85B/cyc) + VALU issue
// ~1380 + serial tail ~900. Wave-count changes couldn't help (r15->r16 -2%);
// the LDS term is structural. Fix: ALL xyz in VGPRs — 192KB payload = 37.5%
// of the CU register file; per thread 96 coord + 32 mind VGPRs, cap 256 at
// launch_bounds(512,2). Staging loads are asm volatile global_load_dwordx4:
// the compiler CANNOT rematerialize volatile-asm outputs (r11/r12 failure
// mode), worst case is a loud scratch spill. Inner loop: pure-VGPR VALU,
// 10 ops/pair, zero LDS traffic.
// Bit-exact: per-lane ((dx^2+dy^2)+dz^2) rn ops, ties -> smallest n via u64
// (monotone-value<<32 | ~index) max reduce.
// ---------------------------------------------------------------------------
__global__ __launch_bounds__(FPS_T, 2) void fps_cnms_kernel(
    const float4* __restrict__ pts, const int* __restrict__ lengths,
    float* __restrict__ centers_out, int* __restrict__ keep_out) {
    const int b = blockIdx.x;
    const int t = threadIdx.x;
    const int lane = t & 63;
    const int wv = t >> 6;                               // 0..7
    const int len = lengths[b];
    const float4* p = pts + (size_t)b * N_;

    __shared__ __align__(16) unsigned long long s_part[2][FPS_W];
    __shared__ float s_cen[G_][3];                        // centers for CNMS

    // Stage ALL 32 points per thread into registers via opaque asm loads.
    // Pair j covers slots 2j (A) and 2j+1 (B); slot s is point n = s*512 + t.
    v2f xp[PPT / 2], yp[PPT / 2], zp[PPT / 2];
    v2f mp[PPT / 2];
#pragma unroll
    for (int j = 0; j < PPT / 2; j += 2) {
        int nA0 = (2 * j) * FPS_T + t;
        float4 qA0, qB0, qA1, qB1;
        const float4* a0 = p + nA0;
        const float4* b0 = a0 + FPS_T;
        const float4* a1 = a0 + 2 * FPS_T;
        const float4* b1 = a0 + 3 * FPS_T;
        asm volatile(
            "global_load_dwordx4 %0, %4, off\n\t"
            "global_load_dwordx4 %1, %5, off\n\t"
            "global_load_dwordx4 %2, %6, off\n\t"
            "global_load_dwordx4 %3, %7, off\n\t"
            "s_waitcnt vmcnt(0)"
            : "=&v"(qA0), "=&v"(qB0), "=&v"(qA1), "=&v"(qB1)
            : "v"(a0), "v"(b0), "v"(a1), "v"(b1)
            : "memory");
        xp[j]     = (v2f){qA0.x, qB0.x};
        yp[j]     = (v2f){qA0.y, qB0.y};
        zp[j]     = (v2f){qA0.z, qB0.z};
        xp[j + 1] = (v2f){qA1.x, qB1.x};
        yp[j + 1] = (v2f){qA1.y, qB1.y};
        zp[j + 1] = (v2f){qA1.z, qB1.z};
        v2f mm0, mm1;
        mm0.x = (nA0 < len)             ? INFINITY : -INFINITY;
        mm0.y = (nA0 + FPS_T < len)     ? INFINITY : -INFINITY;
        mm1.x = (nA0 + 2 * FPS_T < len) ? INFINITY : -INFINITY;
        mm1.y = (nA0 + 3 * FPS_T < len) ? INFINITY : -INFINITY;
        mp[j] = mm0;
        mp[j + 1] = mm1;
    }

    int n = 0;   // winner index (uniform across the block)
    for (int k = 0; k < G_; k++) {
        float4 c = p[n];   // uniform broadcast load (L2-resident)
        if (t == 0) {
            centers_out[(b * G_ + k) * 3 + 0] = c.x;
            centers_out[(b * G_ + k) * 3 + 1] = c.y;
            centers_out[(b * G_ + k) * 3 + 2] = c.z;
            s_cen[k][0] = c.x; s_cen[k][1] = c.y; s_cen[k][2] = c.z;
        }
        if (k == G_ - 1) break;   // last argmax is discarded by the reference

        v2f cXX = {c.x, c.x};
        v2f cYY = {c.y, c.y};
        v2f cZZ = {c.z, c.z};

        // Min-only inner loop: pure-register, 8 pk + 2 v_min per point-pair.
#pragma unroll
        for (int j = 0; j < PPT / 2; j++) {
            v2f dx = xp[j] - cXX;
            v2f dy = yp[j] - cYY;
            v2f dz = zp[j] - cZZ;
            v2f dd = (dx * dx + dy * dy) + dz * dz;       // contract(off): exact
            mp[j] = __builtin_elementwise_min(mp[j], dd);
        }

        // Deferred thread-local value max: balanced tree (fusable to max3).
        v2f t8[8];
#pragma unroll
        for (int j = 0; j < 8; j++)
            t8[j] = __builtin_elementwise_max(mp[2 * j], mp[2 * j + 1]);
        v2f t4a = __builtin_elementwise_max(t8[0], t8[1]);
        v2f t4b = __builtin_elementwise_max(t8[2], t8[3]);
        v2f t4c = __builtin_elementwise_max(t8[4], t8[5]);
        v2f t4d = __builtin_elementwise_max(t8[6], t8[7]);
        v2f t2a = __builtin_elementwise_max(t4a, t4b);
        v2f t2b = __builtin_elementwise_max(t4c, t4d);
        v2f t1 = __builtin_elementwise_max(t2a, t2b);
        float bv = fmaxf(t1.x, t1.y);

        // Smallest slot holding bv; static indices only (no scratch).
        // Within a pair, even slot (x) < odd slot (y); descending j scan.
        int bi = 0;
#pragma unroll
        for (int j = PPT / 2 - 1; j >= 0; j--) {
            bool hx = (mp[j].x == bv);
            bool hy = (mp[j].y == bv);
            int cand = 2 * j + (hx ? 0 : 1);
            if (hx || hy) bi = cand;
        }

        // Monotone u32 key of bv (any non-NaN float, including +-inf).
        unsigned u = __float_as_uint(bv);
        u = (u & 0x80000000u) ? ~u : (u | 0x80000000u);
        int bn = (bi << 9) | t;           // global point index (bi*512 + t)
        unsigned long long v = ((unsigned long long)u << 32) | (unsigned)(~bn);

        // Wave argmax: u64 max == (max value, then min index among ties).
        DPP64_MAXSTEP(v, 0x111, 0xf);     // row_shl 1
        DPP64_MAXSTEP(v, 0x112, 0xf);     // row_shl 2
        DPP64_MAXSTEP(v, 0x114, 0xf);     // row_shl 4
        DPP64_MAXSTEP(v, 0x118, 0xf);     // row_shl 8
        DPP64_MAXSTEP(v, 0x142, 0xa);     // row_bcast15
        DPP64_MAXSTEP(v, 0x143, 0xc);     // row_bcast31 -> lane63 has wave max
        if (lane == 63) s_part[k & 1][wv] = v;
        __syncthreads();

        // Each 8-lane octet reads all 8 partials (same-address broadcast),
        // reduces in 3 DPP steps; readlane(7) broadcasts the winner.
        // Double-buffered s_part => one barrier per step is race-free.
        unsigned long long m = s_part[k & 1][lane & 7];
        DPP64_MAXSTEP(m, 0x111, 0xf);
        DPP64_MAXSTEP(m, 0x112, 0xf);
        DPP64_MAXSTEP(m, 0x114, 0xf);
        unsigned wlo = (unsigned)__builtin_amdgcn_readlane(
            (int)(unsigned)(m & 0xffffffffull), 7);
        n = (int)(~wlo);                  // decode index
    }

    __syncthreads();   // s_cen[127] written by t==0 after the break

    // ---- fused CNMS on wave 0 ----
    if (t < 64) {
        const float THR = (float)((2.0 * 0.1 * (1.0 - 0.7)) * (2.0 * 0.1 * (1.0 - 0.7)));
        float ax = s_cen[t][0],      ay = s_cen[t][1],      az = s_cen[t][2];
        float ex = s_cen[t + 64][0], ey = s_cen[t + 64][1], ez = s_cen[t + 64][2];
        bool k0 = false, k1 = false;
        for (int j = 0; j < G_; j++) {
            float jx = s_cen[j][0], jy = s_cen[j][1], jz = s_cen[j][2];
            bool c0 = k0 && (dist2(ax, ay, az, jx, jy, jz) < THR);
            bool c1 = k1 && (dist2(ex, ey, ez, jx, jy, jz) < THR);
            bool conflict = __any(c0 || c1);
            if (j == t)      k0 = !conflict;
            if (j == t + 64) k1 = !conflict;
        }
        keep_out[b * G_ + t]      = k0 ? 1 : 0;
        keep_out[b * G_ + t + 64] = k1 ? 1 : 0;
    }
}

// ---------------------------------------------------------------------------
// Kernel 2: per-(b,g) ball query (first 128 by index) + top-32 by energy +
// gather/normalize. One 512-thread block per group. (unchanged)
// ---------------------------------------------------------------------------
__global__ __launch_bounds__(BQ_T) void group_kernel(
    const float4* __restrict__ pts, const int* __restrict__ lengths,
    const float* __restrict__ centers, const int* __restrict__ keep,
    float* __restrict__ groups_out, int* __restrict__ gl) {
    const int bid = blockIdx.x;          // b*128 + g
    const int b = bid >> 7;
    const int t = threadIdx.x;
    const int lane = t & 63;
    const int wv = t >> 6;

    const float cx = centers[bid * 3 + 0];
    const float cy = centers[bid * 3 + 1];
    const float cz = centers[bid * 3 + 2];
    float4* out4 = (float4*)(groups_out + (size_t)bid * GS_ * 4);

    if (!keep[bid]) {
        if (t < GS_) {
            float4 o;
            o.x = __fdiv_rn(__fsub_rn(0.f, cx), 0.1f);
            o.y = __fdiv_rn(__fsub_rn(0.f, cy), 0.1f);
            o.z = __fdiv_rn(__fsub_rn(0.f, cz), 0.1f);
            o.w = 0.f;
            out4[t] = o;
        }
        return;
    }

    __shared__ int   s_widx[BQ_W][UK_];
    __shared__ float s_wen[BQ_W][UK_];
    __shared__ int   s_wcnt[BQ_W];
    __shared__ int   s_list[UK_];
    __shared__ float s_en[UK_];
    __shared__ int   s_ord[GS_];

    const int len = lengths[b];
    const float R2 = (float)(0.1 * 0.1);
    const float4* p = pts + (size_t)b * N_;

    // Per-wave ordered stream compaction over its contiguous eighth.
    {
        const int base0 = wv * (N_ / BQ_W);
        int cnt = 0;
        for (int it = 0; it < (N_ / BQ_W) / 64; it++) {
            int n = base0 + it * 64 + lane;
            float4 q = p[n];
            float d2 = dist2(q.x, q.y, q.z, cx, cy, cz);
            bool pred = (n < len) && (d2 <= R2);
            unsigned long long m = __ballot(pred);
            int prefix = __popcll(m & ((1ull << lane) - 1ull));
            int slot = cnt + prefix;
            if (pred && slot < UK_) { s_widx[wv][slot] = n; s_wen[wv][slot] = q.w; }
            cnt += __popcll(m);
        }
        if (lane == 0) s_wcnt[wv] = (cnt < UK_) ? cnt : UK_;
    }
    __syncthreads();

    int M = 0;
#pragma unroll
    for (int w = 0; w < BQ_W; w++) M += s_wcnt[w];
    if (M > UK_) M = UK_;

    // Ordered merge into unified first-M list.
    if (t < UK_ && t < M) {
        int j = t, w = 0;
        while (w < BQ_W - 1 && j >= s_wcnt[w]) { j -= s_wcnt[w]; w++; }
        s_list[t] = s_widx[w][j];
        s_en[t]   = s_wen[w][j];
    }
    __syncthreads();

    // top-32 by energy, tie -> smaller list position (matches lax.top_k)
    if (wv == 0) {
        float v0 = (lane < M) ? s_en[lane] : -INFINITY;
        float v1 = (lane + 64 < M) ? s_en[lane + 64] : -INFINITY;
        for (int k = 0; k < GS_; k++) {
            float bv; int bs;
            if (v0 >= v1) { bv = v0; bs = lane; }
            else          { bv = v1; bs = lane + 64; }
#pragma unroll
            for (int off = 32; off; off >>= 1) {
                float ov = __shfl_xor(bv, off);
                int   os = __shfl_xor(bs, off);
                bool tk = (ov > bv) || (ov == bv && os < bs);
                bv = tk ? ov : bv; bs = tk ? os : bs;
            }
            if (lane == 0) s_ord[k] = (bv == -INFINITY) ? -1 : bs;
            if (bs == lane)           v0 = -INFINITY;
            else if (bs == lane + 64) v1 = -INFINITY;
        }
    }
    __syncthreads();

    if (t < GS_) {
        int o0 = s_ord[0];
        int first = (o0 >= 0) ? s_list[o0] : -1;
        int ok = s_ord[t];
        int ti = (ok >= 0) ? s_list[ok] : -1;
        int f = (ti == -1) ? first : ti;
        float px = 0.f, py = 0.f, pz = 0.f, pw = 0.f;
        if (f >= 0) { float4 q = p[f]; px = q.x; py = q.y; pz = q.z; pw = q.w; }
        float4 o;
        o.x = __fdiv_rn(__fsub_rn(px, cx), 0.1f);
        o.y = __fdiv_rn(__fsub_rn(py, cy), 0.1f);
        o.z = __fdiv_rn(__fsub_rn(pz, cz), 0.1f);
        o.w = __fdiv_rn(pw, 0.1f);
        out4[t] = o;
    }
    if (t == 0 && M >= GS_) atomicAdd(&gl[b], 1);
}

// ---------------------------------------------------------------------------
// Kernel 3: embedding mask
// ---------------------------------------------------------------------------
__global__ void mask_kernel(const int* __restrict__ gl, float* __restrict__ mask_out) {
    int t = threadIdx.x;                 // 1024 threads
    int b = t >> 7, g = t & 127;
    mask_out[t] = (g < gl[b]) ? 1.0f : 0.0f;
}

extern "C" void kernel_launch(void* const* d_in, const int* in_sizes, int n_in,
                              void* d_out, int out_size, void* d_ws, size_t ws_size,
                              hipStream_t stream) {
    const float4* pts = (const float4*)d_in[0];
    const int* lengths = (const int*)d_in[1];
    float* out = (float*)d_out;
    float* groups = out;                               // B*G*GS*4 = 131072
    float* centers = out + (size_t)B_ * G_ * GS_ * 4;  // +3072
    float* mask = centers + (size_t)B_ * G_ * 3;       // +1024
    int* keep = (int*)d_ws;                            // B*G ints
    int* gl = keep + B_ * G_;                          // B ints

    hipLaunchKernelGGL(init_kernel, dim3(1), dim3(64), 0, stream, gl);
    hipLaunchKernelGGL(fps_cnms_kernel, dim3(B_), dim3(FPS_T), 0, stream,
                       pts, lengths, centers, keep);
    hipLaunchKernelGGL(group_kernel, dim3(B_ * G_), dim3(BQ_T), 0, stream,
                       pts, lengths, centers, keep, groups, gl);
    hipLaunchKernelGGL(mask_kernel, dim3(1), dim3(B_ * G_), 0, stream, gl, mask);
}

// Round 8
// 291.981 us; speedup vs baseline: 1.1095x; 1.1095x over previous
//
#include <hip/hip_runtime.h>
#include <math.h>

#define B_ 8
#define N_ 16384
#define G_ 128      // NUM_GROUPS
#define GS_ 32      // GROUP_SIZE
#define UK_ 128     // UPSCALE_K
#define FPS_T 512
#define FPS_W 8     // waves per FPS block
#define FPS_BLK 4   // blocks (slices) per batch, stride-8 blockIdx => same XCD
#define SLICE (N_ / FPS_BLK)     // 4096 points per block
#define PPT (SLICE / FPS_T)      // 8 points per thread, all coords in VGPRs
#define BQ_T 512
#define BQ_W 8      // waves per group block

// No mul+add contraction anywhere in this TU: per-op IEEE rounding must match
// the numpy reference exactly (((dx*dx + dy*dy) + dz*dz), each op rounded).
#pragma clang fp contract(off)

typedef float v2f __attribute__((ext_vector_type(2)));

// 64-bit max-combine with a DPP-shifted copy of vv (old=0 == identity for max).
#define DPP64_MAXSTEP(vv, ctrl, rmask)                                          \
  {                                                                             \
    unsigned _lo = (unsigned)__builtin_amdgcn_update_dpp(                       \
        0, (int)(unsigned)((vv) & 0xffffffffull), (ctrl), (rmask), 0xf, false); \
    unsigned _hi = (unsigned)__builtin_amdgcn_update_dpp(                       \
        0, (int)(unsigned)((vv) >> 32), (ctrl), (rmask), 0xf, false);           \
    unsigned long long _tv = ((unsigned long long)_hi << 32) | _lo;             \
    if (_tv > (vv)) (vv) = _tv;                                                 \
  }

__device__ __forceinline__ unsigned long long shfl_xor_u64(unsigned long long v, int m) {
    int lo = __shfl_xor((int)(unsigned)(v & 0xffffffffull), m);
    int hi = __shfl_xor((int)(unsigned)(v >> 32), m);
    return ((unsigned long long)(unsigned)hi << 32) | (unsigned)lo;
}

__device__ __forceinline__ unsigned long long umax64(unsigned long long a,
                                                     unsigned long long b) {
    return a > b ? a : b;
}

// Exact-rounding distance^2, matching numpy: ((dx*dx + dy*dy) + dz*dz), no FMA.
__device__ __forceinline__ float dist2(float x, float y, float z,
                                       float cx, float cy, float cz) {
    float dx = __fsub_rn(x, cx);
    float dy = __fsub_rn(y, cy);
    float dz = __fsub_rn(z, cz);
    return __fadd_rn(__fadd_rn(__fmul_rn(dx, dx), __fmul_rn(dy, dy)),
                     __fmul_rn(dz, dz));
}

// ---------------------------------------------------------------------------
// Kernel 0: zero the cross-block slots + gl (ws is poisoned 0xAA; must be
// stream-ordered BEFORE fps so no block can see poison as a valid key).
// ---------------------------------------------------------------------------
__global__ void init_kernel(unsigned long long* __restrict__ slots,
                            int* __restrict__ gl) {
    int t = threadIdx.x;                 // 1024 threads
#pragma unroll
    for (int i = 0; i < (B_ * G_ * FPS_BLK) / 1024; i++)
        slots[i * 1024 + t] = 0ull;
    if (t < B_) gl[t] = 0;
}

// ---------------------------------------------------------------------------
// Kernel 1: FPS, 4 blocks per batch (4096 pts each) + fused CNMS (slice 0).
//
// r18 synthesis: r15/r16/r17 (single-block variants: LDS-resident, fewer
// waves, reg/AGPR-resident) ALL land at ~4300 cyc/step — step time is the
// serial chain, invariant to coordinate residence. r10 (4 blk/batch, 212us)
// is still fastest: blocks b,b+8,b+16,b+24 share an XCD under round-robin
// dispatch, so the slot merge resolves in that XCD's L2 (~250cyc), and the
// distance+reduce work is quartered. This round: r10's split + r16's lean
// structure — 512 thr, PPT=8, coords in regs (asm-staged, 24 payload regs),
// pk math, ONE barrier/step (all waves redundantly reduce partials and poll
// the 3 remote slots; no second barrier / s_bcn hop).
// Bit-exact: per-lane ((dx^2+dy^2)+dz^2) rn, global ties -> smallest n via
// u64 (monotone-value<<32 | ~n) max across waves AND blocks.
// ---------------------------------------------------------------------------
__global__ __launch_bounds__(FPS_T, 2) void fps_cnms_kernel(
    const float4* __restrict__ pts, const int* __restrict__ lengths,
    float* __restrict__ centers_out, int* __restrict__ keep_out,
    unsigned long long* __restrict__ slots) {
    const int b = blockIdx.x & 7;        // batch (== XCD under round-robin)
    const int slice = blockIdx.x >> 3;   // 0..3
    const int t = threadIdx.x;
    const int lane = t & 63;
    const int wv = t >> 6;               // 0..7
    const int len = lengths[b];
    const float4* p = pts + (size_t)b * N_;
    const int base = slice * SLICE;

    __shared__ __align__(16) unsigned long long s_part[2][FPS_W];
    __shared__ float s_cen[G_][3];                        // centers (slice 0)

    // Stage all 8 points per thread into registers via opaque asm loads
    // (compiler cannot rematerialize volatile-asm outputs; 24 payload regs).
    // Pair j covers slots 2j (A) and 2j+1 (B); slot s is n = base + s*512 + t.
    v2f xp[PPT / 2], yp[PPT / 2], zp[PPT / 2];
    v2f mp[PPT / 2];
#pragma unroll
    for (int j = 0; j < PPT / 2; j += 2) {
        int nA0 = base + (2 * j) * FPS_T + t;
        float4 qA0, qB0, qA1, qB1;
        const float4* a0 = p + nA0;
        const float4* b0 = a0 + FPS_T;
        const float4* a1 = a0 + 2 * FPS_T;
        const float4* b1 = a0 + 3 * FPS_T;
        asm volatile(
            "global_load_dwordx4 %0, %4, off\n\t"
            "global_load_dwordx4 %1, %5, off\n\t"
            "global_load_dwordx4 %2, %6, off\n\t"
            "global_load_dwordx4 %3, %7, off\n\t"
            "s_waitcnt vmcnt(0)"
            : "=&v"(qA0), "=&v"(qB0), "=&v"(qA1), "=&v"(qB1)
            : "v"(a0), "v"(b0), "v"(a1), "v"(b1)
            : "memory");
        xp[j]     = (v2f){qA0.x, qB0.x};
        yp[j]     = (v2f){qA0.y, qB0.y};
        zp[j]     = (v2f){qA0.z, qB0.z};
        xp[j + 1] = (v2f){qA1.x, qB1.x};
        yp[j + 1] = (v2f){qA1.y, qB1.y};
        zp[j + 1] = (v2f){qA1.z, qB1.z};
        v2f mm0, mm1;
        mm0.x = (nA0 < len)             ? INFINITY : -INFINITY;
        mm0.y = (nA0 + FPS_T < len)     ? INFINITY : -INFINITY;
        mm1.x = (nA0 + 2 * FPS_T < len) ? INFINITY : -INFINITY;
        mm1.y = (nA0 + 3 * FPS_T < len) ? INFINITY : -INFINITY;
        mp[j] = mm0;
        mp[j + 1] = mm1;
    }

    int n = 0;   // winner index (uniform across ALL blocks of batch b)
    for (int k = 0; k < G_; k++) {
        float4 c = p[n];   // uniform broadcast load (own-XCD L2)
        if (slice == 0 && t == 0) {
            centers_out[(b * G_ + k) * 3 + 0] = c.x;
            centers_out[(b * G_ + k) * 3 + 1] = c.y;
            centers_out[(b * G_ + k) * 3 + 2] = c.z;
            s_cen[k][0] = c.x; s_cen[k][1] = c.y; s_cen[k][2] = c.z;
        }
        if (k == G_ - 1) break;   // last argmax is discarded by the reference

        v2f cXX = {c.x, c.x};
        v2f cYY = {c.y, c.y};
        v2f cZZ = {c.z, c.z};

        // Min-only inner loop: pure-register, 8 pk + 2 v_min per point-pair.
#pragma unroll
        for (int j = 0; j < PPT / 2; j++) {
            v2f dx = xp[j] - cXX;
            v2f dy = yp[j] - cYY;
            v2f dz = zp[j] - cZZ;
            v2f dd = (dx * dx + dy * dy) + dz * dz;       // contract(off): exact
            mp[j] = __builtin_elementwise_min(mp[j], dd);
        }

        // Deferred thread-local value max (balanced tree).
        v2f t2a = __builtin_elementwise_max(mp[0], mp[1]);
        v2f t2b = __builtin_elementwise_max(mp[2], mp[3]);
        v2f t1  = __builtin_elementwise_max(t2a, t2b);
        float bv = fmaxf(t1.x, t1.y);

        // Smallest slot holding bv (even slot .x < odd slot .y in a pair).
        int bi = 0;
#pragma unroll
        for (int j = PPT / 2 - 1; j >= 0; j--) {
            bool hx = (mp[j].x == bv);
            bool hy = (mp[j].y == bv);
            int cand = 2 * j + (hx ? 0 : 1);
            if (hx || hy) bi = cand;
        }

        // Monotone u32 key of bv (any non-NaN float, incl. +-inf; never 0).
        unsigned u = __float_as_uint(bv);
        u = (u & 0x80000000u) ? ~u : (u | 0x80000000u);
        int bn = base | (bi << 9) | t;    // global point index in batch
        unsigned long long v = ((unsigned long long)u << 32) | (unsigned)(~bn);

        // Wave argmax: u64 max == (max value, then min index among ties).
        DPP64_MAXSTEP(v, 0x111, 0xf);     // row_shl 1
        DPP64_MAXSTEP(v, 0x112, 0xf);     // row_shl 2
        DPP64_MAXSTEP(v, 0x114, 0xf);     // row_shl 4
        DPP64_MAXSTEP(v, 0x118, 0xf);     // row_shl 8
        DPP64_MAXSTEP(v, 0x142, 0xa);     // row_bcast15
        DPP64_MAXSTEP(v, 0x143, 0xc);     // row_bcast31 -> lane63 has wave max
        if (lane == 63) s_part[k & 1][wv] = v;
        __syncthreads();

        // Every wave redundantly reduces the 8 partials (3 DPP steps) -> block
        // key kk, then polls the 3 REMOTE slots itself (lane==slice keeps kk).
        // One barrier per step; double-buffered s_part is race-free.
        unsigned long long m = s_part[k & 1][lane & 7];
        DPP64_MAXSTEP(m, 0x111, 0xf);
        DPP64_MAXSTEP(m, 0x112, 0xf);
        DPP64_MAXSTEP(m, 0x114, 0xf);
        unsigned klo = (unsigned)__builtin_amdgcn_readlane(
            (int)(unsigned)(m & 0xffffffffull), 7);
        unsigned khi = (unsigned)__builtin_amdgcn_readlane(
            (int)(unsigned)(m >> 32), 7);
        unsigned long long kk = ((unsigned long long)khi << 32) | klo;

        unsigned long long* slot = slots + ((size_t)b * G_ + k) * FPS_BLK;
        if (wv == 0 && lane == 0)
            __hip_atomic_store(&slot[slice], kk, __ATOMIC_RELAXED,
                               __HIP_MEMORY_SCOPE_AGENT);
        unsigned long long pv = kk;       // own block's key for lane==slice
        if (lane < FPS_BLK && lane != slice) {
            do {
                pv = __hip_atomic_load(&slot[lane], __ATOMIC_RELAXED,
                                       __HIP_MEMORY_SCOPE_AGENT);
            } while (pv == 0ull);
        }
        // Merge lanes 0..3; lane0's result is the global winner; broadcast.
        unsigned long long mg = umax64(pv, shfl_xor_u64(pv, 1));
        mg = umax64(mg, shfl_xor_u64(mg, 2));
        unsigned wlo = (unsigned)__builtin_amdgcn_readfirstlane(
            (int)(unsigned)(mg & 0xffffffffull));
        n = (int)(~wlo);                  // decode index
    }

    __syncthreads();   // s_cen[127] written by t==0 after the break

    // ---- fused CNMS on wave 0 of the slice-0 block ----
    if (slice == 0 && t < 64) {
        const float THR = (float)((2.0 * 0.1 * (1.0 - 0.7)) * (2.0 * 0.1 * (1.0 - 0.7)));
        float ax = s_cen[t][0],      ay = s_cen[t][1],      az = s_cen[t][2];
        float ex = s_cen[t + 64][0], ey = s_cen[t + 64][1], ez = s_cen[t + 64][2];
        bool k0 = false, k1 = false;
        for (int j = 0; j < G_; j++) {
            float jx = s_cen[j][0], jy = s_cen[j][1], jz = s_cen[j][2];
            bool c0 = k0 && (dist2(ax, ay, az, jx, jy, jz) < THR);
            bool c1 = k1 && (dist2(ex, ey, ez, jx, jy, jz) < THR);
            bool conflict = __any(c0 || c1);
            if (j == t)      k0 = !conflict;
            if (j == t + 64) k1 = !conflict;
        }
        keep_out[b * G_ + t]      = k0 ? 1 : 0;
        keep_out[b * G_ + t + 64] = k1 ? 1 : 0;
    }
}

// ---------------------------------------------------------------------------
// Kernel 2: per-(b,g) ball query (first 128 by index) + top-32 by energy +
// gather/normalize. One 512-thread block per group. (unchanged)
// ---------------------------------------------------------------------------
__global__ __launch_bounds__(BQ_T) void group_kernel(
    const float4* __restrict__ pts, const int* __restrict__ lengths,
    const float* __restrict__ centers, const int* __restrict__ keep,
    float* __restrict__ groups_out, int* __restrict__ gl) {
    const int bid = blockIdx.x;          // b*128 + g
    const int b = bid >> 7;
    const int t = threadIdx.x;
    const int lane = t & 63;
    const int wv = t >> 6;

    const float cx = centers[bid * 3 + 0];
    const float cy = centers[bid * 3 + 1];
    const float cz = centers[bid * 3 + 2];
    float4* out4 = (float4*)(groups_out + (size_t)bid * GS_ * 4);

    if (!keep[bid]) {
        if (t < GS_) {
            float4 o;
            o.x = __fdiv_rn(__fsub_rn(0.f, cx), 0.1f);
            o.y = __fdiv_rn(__fsub_rn(0.f, cy), 0.1f);
            o.z = __fdiv_rn(__fsub_rn(0.f, cz), 0.1f);
            o.w = 0.f;
            out4[t] = o;
        }
        return;
    }

    __shared__ int   s_widx[BQ_W][UK_];
    __shared__ float s_wen[BQ_W][UK_];
    __shared__ int   s_wcnt[BQ_W];
    __shared__ int   s_list[UK_];
    __shared__ float s_en[UK_];
    __shared__ int   s_ord[GS_];

    const int len = lengths[b];
    const float R2 = (float)(0.1 * 0.1);
    const float4* p = pts + (size_t)b * N_;

    // Per-wave ordered stream compaction over its contiguous eighth.
    {
        const int base0 = wv * (N_ / BQ_W);
        int cnt = 0;
        for (int it = 0; it < (N_ / BQ_W) / 64; it++) {
            int n = base0 + it * 64 + lane;
            float4 q = p[n];
            float d2 = dist2(q.x, q.y, q.z, cx, cy, cz);
            bool pred = (n < len) && (d2 <= R2);
            unsigned long long m = __ballot(pred);
            int prefix = __popcll(m & ((1ull << lane) - 1ull));
            int slot = cnt + prefix;
            if (pred && slot < UK_) { s_widx[wv][slot] = n; s_wen[wv][slot] = q.w; }
            cnt += __popcll(m);
        }
        if (lane == 0) s_wcnt[wv] = (cnt < UK_) ? cnt : UK_;
    }
    __syncthreads();

    int M = 0;
#pragma unroll
    for (int w = 0; w < BQ_W; w++) M += s_wcnt[w];
    if (M > UK_) M = UK_;

    // Ordered merge into unified first-M list.
    if (t < UK_ && t < M) {
        int j = t, w = 0;
        while (w < BQ_W - 1 && j >= s_wcnt[w]) { j -= s_wcnt[w]; w++; }
        s_list[t] = s_widx[w][j];
        s_en[t]   = s_wen[w][j];
    }
    __syncthreads();

    // top-32 by energy, tie -> smaller list position (matches lax.top_k)
    if (wv == 0) {
        float v0 = (lane < M) ? s_en[lane] : -INFINITY;
        float v1 = (lane + 64 < M) ? s_en[lane + 64] : -INFINITY;
        for (int k = 0; k < GS_; k++) {
            float bv; int bs;
            if (v0 >= v1) { bv = v0; bs = lane; }
            else          { bv = v1; bs = lane + 64; }
#pragma unroll
            for (int off = 32; off; off >>= 1) {
                float ov = __shfl_xor(bv, off);
                int   os = __shfl_xor(bs, off);
                bool tk = (ov > bv) || (ov == bv && os < bs);
                bv = tk ? ov : bv; bs = tk ? os : bs;
            }
            if (lane == 0) s_ord[k] = (bv == -INFINITY) ? -1 : bs;
            if (bs == lane)           v0 = -INFINITY;
            else if (bs == lane + 64) v1 = -INFINITY;
        }
    }
    __syncthreads();

    if (t < GS_) {
        int o0 = s_ord[0];
        int first = (o0 >= 0) ? s_list[o0] : -1;
        int ok = s_ord[t];
        int ti = (ok >= 0) ? s_list[ok] : -1;
        int f = (ti == -1) ? first : ti;
        float px = 0.f, py = 0.f, pz = 0.f, pw = 0.f;
        if (f >= 0) { float4 q = p[f]; px = q.x; py = q.y; pz = q.z; pw = q.w; }
        float4 o;
        o.x = __fdiv_rn(__fsub_rn(px, cx), 0.1f);
        o.y = __fdiv_rn(__fsub_rn(py, cy), 0.1f);
        o.z = __fdiv_rn(__fsub_rn(pz, cz), 0.1f);
        o.w = __fdiv_rn(pw, 0.1f);
        out4[t] = o;
    }
    if (t == 0 && M >= GS_) atomicAdd(&gl[b], 1);
}

// ---------------------------------------------------------------------------
// Kernel 3: embedding mask
// ---------------------------------------------------------------------------
__global__ void mask_kernel(const int* __restrict__ gl, float* __restrict__ mask_out) {
    int t = threadIdx.x;                 // 1024 threads
    int b = t >> 7, g = t & 127;
    mask_out[t] = (g < gl[b]) ? 1.0f : 0.0f;
}

extern "C" void kernel_launch(void* const* d_in, const int* in_sizes, int n_in,
                              void* d_out, int out_size, void* d_ws, size_t ws_size,
                              hipStream_t stream) {
    const float4* pts = (const float4*)d_in[0];
    const int* lengths = (const int*)d_in[1];
    float* out = (float*)d_out;
    float* groups = out;                               // B*G*GS*4 = 131072
    float* centers = out + (size_t)B_ * G_ * GS_ * 4;  // +3072
    float* mask = centers + (size_t)B_ * G_ * 3;       // +1024
    unsigned long long* slots = (unsigned long long*)d_ws;  // B*G*FPS_BLK u64
    int* keep = (int*)(slots + B_ * G_ * FPS_BLK);     // B*G ints
    int* gl = keep + B_ * G_;                          // B ints

    hipLaunchKernelGGL(init_kernel, dim3(1), dim3(1024), 0, stream, slots, gl);
    hipLaunchKernelGGL(fps_cnms_kernel, dim3(B_ * FPS_BLK), dim3(FPS_T), 0, stream,
                       pts, lengths, centers, keep, slots);
    hipLaunchKernelGGL(group_kernel, dim3(B_ * G_), dim3(BQ_T), 0, stream,
                       pts, lengths, centers, keep, groups, gl);
    hipLaunchKernelGGL(mask_kernel, dim3(1), dim3(B_ * G_), 0, stream, gl, mask);
}